// Round 1
// baseline (262.222 us; speedup 1.0000x reference)
//
#include <hip/hip_runtime.h>
#include <hip/hip_bf16.h>

// Problem dims (fixed by reference setup_inputs)
#define M_DIM 32
#define K_DIM 8192
#define N_DIM 8192
#define KS 8                      // K-split factor
#define KCH (K_DIM / KS)          // 1024 k per wave
#define NGROUPS (N_DIM / 32)      // 256 wave n-groups (32 n each)
#define TOTAL_WAVES (NGROUPS * KS)  // 2048
#define MAIN_BLOCKS (TOTAL_WAVES / 4)  // 512 blocks of 256 threads

typedef _Float16 half8 __attribute__((ext_vector_type(8)));
typedef float floatx4 __attribute__((ext_vector_type(4)));

// Decode one packed byte (2 fp4 nibbles, low = even k, high = odd k) into
// packed 2xf16 bits. E2M1: mag code m -> f16 exp/mant bits t<<9 with
// t = 0,28,30,31,32,33,34,35 for m=0..7 (0, .5, 1, 1.5, 2, 3, 4, 6).
__device__ __forceinline__ uint32_t dec2(uint32_t q) {
  uint32_t c0 = q & 0xFu, c1 = (q >> 4) & 0xFu;
  uint32_t m0 = c0 & 7u, m1 = c1 & 7u;
  uint32_t t0 = (m0 >= 2u) ? (m0 + 28u) : (m0 ? 28u : 0u);
  uint32_t t1 = (m1 >= 2u) ? (m1 + 28u) : (m1 ? 28u : 0u);
  return (t0 << 9) | ((c0 & 8u) << 12)   // half0: mag bits 9-14, sign bit3->15
       | (t1 << 25) | ((c1 & 8u) << 28); // half1: <<16 on top of the same
}

// 4 packed int32 (8 consecutive fp4 along k) -> half8 B-fragment, times scale.
__device__ __forceinline__ half8 decode8(int4 q, float scale) {
  union { uint32_t u[4]; half8 h; } w;
  w.u[0] = dec2((uint32_t)q.x);
  w.u[1] = dec2((uint32_t)q.y);
  w.u[2] = dec2((uint32_t)q.z);
  w.u[3] = dec2((uint32_t)q.w);
  _Float16 s = (_Float16)scale;
  half8 sv = {s, s, s, s, s, s, s, s};
  return w.h * sv;  // v_pk_mul_f16 x4
}

// Load A-fragment: in[m][kq .. kq+7] as f16 (amax pre-folded into scales side).
__device__ __forceinline__ half8 loadA(const float* __restrict__ inp, int m, int kq) {
  const floatx4* p = reinterpret_cast<const floatx4*>(inp + m * K_DIM + kq);
  floatx4 f0 = p[0];
  floatx4 f1 = p[1];
  half8 a;
  a[0] = (_Float16)f0[0]; a[1] = (_Float16)f0[1];
  a[2] = (_Float16)f0[2]; a[3] = (_Float16)f0[3];
  a[4] = (_Float16)f1[0]; a[5] = (_Float16)f1[1];
  a[6] = (_Float16)f1[2]; a[7] = (_Float16)f1[3];
  return a;
}

// out[m][n] = bias[n] (runs before main kernel on same stream)
__global__ void init_out_kernel(float* __restrict__ out, const float* __restrict__ bias) {
  int idx = blockIdx.x * blockDim.x + threadIdx.x;
  if (idx < M_DIM * N_DIM) out[idx] = bias[idx & (N_DIM - 1)];
}

__global__ __launch_bounds__(256, 2) void fp4_linear_kernel(
    const float* __restrict__ inp,     // [32, 8192] f32
    const int4*  __restrict__ qw4,     // [8192, 1024] int4 (= [N, K/2] int32)
    const float* __restrict__ scales,  // [8192, 512] f32
    const float* __restrict__ amaxp,   // [1]
    float* __restrict__ out)           // [32, 8192] f32 (pre-filled with bias)
{
  const int lane = threadIdx.x & 63;
  const int wave = blockIdx.x * 4 + (threadIdx.x >> 6);
  const int ng   = wave & (NGROUPS - 1);   // which 32-wide n group
  const int ks   = wave >> 8;              // which K slice (log2(NGROUPS)=8)
  const int n0   = ng * 32;
  const int kb   = ks * KCH;

  const int row  = lane & 15;   // n-within-tile for B, m-within-tile for A
  const int quad = lane >> 4;   // selects which 8 k's of the 32-k MFMA step

  const float amax = amaxp[0];

  floatx4 acc00 = {0.f, 0.f, 0.f, 0.f};  // m-tile0 x n-tile0
  floatx4 acc01 = {0.f, 0.f, 0.f, 0.f};  // m-tile0 x n-tile1
  floatx4 acc10 = {0.f, 0.f, 0.f, 0.f};  // m-tile1 x n-tile0
  floatx4 acc11 = {0.f, 0.f, 0.f, 0.f};  // m-tile1 x n-tile1

  const int nA = n0 + row;
  const int nB = n0 + 16 + row;
  const int4*  qrowA = qw4 + (size_t)nA * (K_DIM / 8);
  const int4*  qrowB = qw4 + (size_t)nB * (K_DIM / 8);
  const float* srowA = scales + (size_t)nA * (K_DIM / 16);
  const float* srowB = scales + (size_t)nB * (K_DIM / 16);

  for (int k0 = kb; k0 < kb + KCH; k0 += 32) {
    const int kq = k0 + quad * 8;        // this lane's 8 k's
    // B fragments: 8 consecutive fp4 of one weight row = one dwordx4
    int4  qA = qrowA[kq >> 3];
    int4  qB = qrowB[kq >> 3];
    float sA = srowA[kq >> 4] * amax;    // 8 k's sit inside one 16-block
    float sB = srowB[kq >> 4] * amax;
    half8 bA = decode8(qA, sA);
    half8 bB = decode8(qB, sB);
    // A fragments: two m tiles
    half8 a0 = loadA(inp, row, kq);
    half8 a1 = loadA(inp, row + 16, kq);

    acc00 = __builtin_amdgcn_mfma_f32_16x16x32_f16(a0, bA, acc00, 0, 0, 0);
    acc01 = __builtin_amdgcn_mfma_f32_16x16x32_f16(a0, bB, acc01, 0, 0, 0);
    acc10 = __builtin_amdgcn_mfma_f32_16x16x32_f16(a1, bA, acc10, 0, 0, 0);
    acc11 = __builtin_amdgcn_mfma_f32_16x16x32_f16(a1, bB, acc11, 0, 0, 0);
  }

  // Epilogue: D layout col = lane&15 (n), row = quad*4 + reg (m).
#pragma unroll
  for (int r = 0; r < 4; ++r) {
    const int m = quad * 4 + r;
    unsafeAtomicAdd(&out[(size_t)m * N_DIM + n0 + row],            acc00[r]);
    unsafeAtomicAdd(&out[(size_t)m * N_DIM + n0 + 16 + row],       acc01[r]);
    unsafeAtomicAdd(&out[(size_t)(m + 16) * N_DIM + n0 + row],      acc10[r]);
    unsafeAtomicAdd(&out[(size_t)(m + 16) * N_DIM + n0 + 16 + row], acc11[r]);
  }
}

extern "C" void kernel_launch(void* const* d_in, const int* in_sizes, int n_in,
                              void* d_out, int out_size, void* d_ws, size_t ws_size,
                              hipStream_t stream) {
  const float* inp    = (const float*)d_in[0];
  const int4*  qw4    = (const int4*)d_in[1];
  const float* scales = (const float*)d_in[2];
  const float* amaxp  = (const float*)d_in[3];
  const float* bias   = (const float*)d_in[4];
  float* out = (float*)d_out;

  init_out_kernel<<<(M_DIM * N_DIM + 255) / 256, 256, 0, stream>>>(out, bias);
  fp4_linear_kernel<<<MAIN_BLOCKS, 256, 0, stream>>>(inp, qw4, scales, amaxp, out);
}

// Round 2
// 236.697 us; speedup vs baseline: 1.1078x; 1.1078x over previous
//
#include <hip/hip_runtime.h>
#include <hip/hip_bf16.h>

// Problem dims (fixed by reference setup_inputs)
#define M_DIM 32
#define K_DIM 8192
#define N_DIM 8192
#define KS 16                        // K-split factor (slices)
#define KCH (K_DIM / KS)             // 512 k per wave
#define ITERS (KCH / 32)             // 16 MFMA k-steps per wave
#define NGROUPS (N_DIM / 32)         // 256 n-groups of 32 columns
#define MAIN_BLOCKS (NGROUPS * KS / 4)  // 1024 blocks: 4 waves = 4 k-slices

typedef _Float16 half8   __attribute__((ext_vector_type(8)));
typedef _Float16 half4_t __attribute__((ext_vector_type(4)));
typedef _Float16 half2_t __attribute__((ext_vector_type(2)));
typedef float    floatx4 __attribute__((ext_vector_type(4)));

#if defined(__has_builtin)
#if __has_builtin(__builtin_amdgcn_cvt_scalef32_pk_f16_fp4)
#define HAVE_CVT_FP4 1
#endif
#endif

// ---- FP4 E2M1 decode: one payload byte per int32 (reference uses only low 8
// bits of each qweight int32 -> 2 fp4 values). 4 dwords -> 8 f16 * scale. ----
#ifndef HAVE_CVT_FP4
// Manual bit-decode fallback: mag code m -> f16 bits t<<9,
// t = min(28*m, m+28) = [0,28,30,31,32,33,34,35]; sign bit3 -> bit15.
__device__ __forceinline__ uint32_t dec2(uint32_t q) {
  uint32_t c0 = q & 0xFu, c1 = (q >> 4) & 0xFu;
  uint32_t m0 = c0 & 7u, m1 = c1 & 7u;
  uint32_t t0 = min(28u * m0, m0 + 28u);
  uint32_t t1 = min(28u * m1, m1 + 28u);
  return (t0 << 9) | ((c0 & 8u) << 12)
       | (t1 << 25) | ((c1 & 8u) << 28);
}
#endif

__device__ __forceinline__ half8 decode8(int4 q, float scale) {
  union { uint32_t u[4]; half2_t h2[4]; half8 h; } w;
#ifdef HAVE_CVT_FP4
  // HW fp4->f16 converter. scale operand pinned to 1.0 (identity under any
  // plausible scale semantics); real scale applied via pk_mul below.
  w.h2[0] = __builtin_amdgcn_cvt_scalef32_pk_f16_fp4((unsigned)q.x, 1.0f, 0);
  w.h2[1] = __builtin_amdgcn_cvt_scalef32_pk_f16_fp4((unsigned)q.y, 1.0f, 0);
  w.h2[2] = __builtin_amdgcn_cvt_scalef32_pk_f16_fp4((unsigned)q.z, 1.0f, 0);
  w.h2[3] = __builtin_amdgcn_cvt_scalef32_pk_f16_fp4((unsigned)q.w, 1.0f, 0);
#else
  w.u[0] = dec2((uint32_t)q.x);
  w.u[1] = dec2((uint32_t)q.y);
  w.u[2] = dec2((uint32_t)q.z);
  w.u[3] = dec2((uint32_t)q.w);
#endif
  _Float16 s = (_Float16)scale;
  half8 sv = {s, s, s, s, s, s, s, s};
  return w.h * sv;  // 4x v_pk_mul_f16
}

// A-fragment load: f16 path (pre-converted in ws) or f32 direct.
template <bool F16A>
__device__ __forceinline__ half8 loadA(const void* __restrict__ A, int m, int kq) {
  if constexpr (F16A) {
    return *reinterpret_cast<const half8*>(
        (const _Float16*)A + (size_t)m * K_DIM + kq);
  } else {
    const floatx4* p =
        reinterpret_cast<const floatx4*>((const float*)A + (size_t)m * K_DIM + kq);
    floatx4 f0 = p[0];
    floatx4 f1 = p[1];
    half8 a;
    a[0] = (_Float16)f0[0]; a[1] = (_Float16)f0[1];
    a[2] = (_Float16)f0[2]; a[3] = (_Float16)f0[3];
    a[4] = (_Float16)f1[0]; a[5] = (_Float16)f1[1];
    a[6] = (_Float16)f1[2]; a[7] = (_Float16)f1[3];
    return a;
  }
}

// out[m][n] = bias[n], vectorized float4. 65536 float4s.
__global__ void init_out_kernel(floatx4* __restrict__ out4,
                                const floatx4* __restrict__ bias4) {
  int idx = blockIdx.x * blockDim.x + threadIdx.x;
  out4[idx] = bias4[idx & (N_DIM / 4 - 1)];
}

// inp f32 -> ws f16, vectorized. 65536 float4s.
__global__ void convertA_kernel(const floatx4* __restrict__ in4,
                                half4_t* __restrict__ out4) {
  int idx = blockIdx.x * blockDim.x + threadIdx.x;
  floatx4 f = in4[idx];
  half4_t h;
  h[0] = (_Float16)f[0]; h[1] = (_Float16)f[1];
  h[2] = (_Float16)f[2]; h[3] = (_Float16)f[3];
  out4[idx] = h;
}

template <bool F16A>
__global__ __launch_bounds__(256, 4) void fp4_linear_kernel(
    const void* __restrict__ Av,       // [32, 8192] f16 (ws) or f32 (input)
    const int4* __restrict__ qw4,      // [8192][1024] int4 view of [N, K/2] i32
    const float* __restrict__ scales,  // [8192, 512] f32
    const float* __restrict__ amaxp,   // [1]
    float* __restrict__ out)           // [32, 8192] f32, pre-filled with bias
{
  const int lane = threadIdx.x & 63;
  const int w    = threadIdx.x >> 6;        // wave in block = k-slice sub-id
  const int ng   = blockIdx.x >> 2;         // n-group (32 columns)
  const int ks   = (blockIdx.x & 3) * 4 + w;  // this wave's k-slice [0,16)
  const int n0   = ng * 32;
  const int kb   = ks * KCH;

  const int row  = lane & 15;   // n-within-tile (B) / m-within-tile (A)
  const int quad = lane >> 4;   // which 8 k's of the 32-k MFMA step

  const float amax = amaxp[0];

  floatx4 acc00 = {0.f, 0.f, 0.f, 0.f};
  floatx4 acc01 = {0.f, 0.f, 0.f, 0.f};
  floatx4 acc10 = {0.f, 0.f, 0.f, 0.f};
  floatx4 acc11 = {0.f, 0.f, 0.f, 0.f};

  const int nA = n0 + row;
  const int nB = n0 + 16 + row;
  const int4*  qrowA = qw4 + (size_t)nA * (K_DIM / 8);
  const int4*  qrowB = qw4 + (size_t)nB * (K_DIM / 8);
  const float* srowA = scales + (size_t)nA * (K_DIM / 16);
  const float* srowB = scales + (size_t)nB * (K_DIM / 16);

  // Software pipeline: iter 0 preload, then prefetch next inside the loop.
  int kq = kb + quad * 8;
  int4  qA = qrowA[kq >> 3];
  int4  qB = qrowB[kq >> 3];
  float sA = srowA[kq >> 4];
  float sB = srowB[kq >> 4];
  half8 a0 = loadA<F16A>(Av, row, kq);
  half8 a1 = loadA<F16A>(Av, row + 16, kq);

#pragma unroll 4
  for (int it = 0; it < ITERS; ++it) {
    const int kqn  = kq + 32;
    const int qidx = min(kqn >> 3, K_DIM / 8 - 1);   // clamp: last-iter peel
    const int sidx = min(kqn >> 4, K_DIM / 16 - 1);
    const int aidx = min(kqn, K_DIM - 8);
    int4  qA_n = qrowA[qidx];
    int4  qB_n = qrowB[qidx];
    float sA_n = srowA[sidx];
    float sB_n = srowB[sidx];
    half8 a0_n = loadA<F16A>(Av, row, aidx);
    half8 a1_n = loadA<F16A>(Av, row + 16, aidx);

    half8 bA = decode8(qA, sA * amax);
    half8 bB = decode8(qB, sB * amax);
    acc00 = __builtin_amdgcn_mfma_f32_16x16x32_f16(a0, bA, acc00, 0, 0, 0);
    acc01 = __builtin_amdgcn_mfma_f32_16x16x32_f16(a0, bB, acc01, 0, 0, 0);
    acc10 = __builtin_amdgcn_mfma_f32_16x16x32_f16(a1, bA, acc10, 0, 0, 0);
    acc11 = __builtin_amdgcn_mfma_f32_16x16x32_f16(a1, bB, acc11, 0, 0, 0);

    qA = qA_n; qB = qB_n; sA = sA_n; sB = sB_n; a0 = a0_n; a1 = a1_n;
    kq = kqn;
  }

  // ---- Cross-wave (4 k-slices) LDS reduction, then 1 atomic per output. ----
  // D layout: col = lane&15 (n), row = quad*4 + reg (m). Stride 34 floats:
  // bank = (2m+n)%32 -> only 2-way aliasing on writes (free).
  __shared__ float red[4 * 32 * 34];
  float* slab = red + w * (32 * 34);
#pragma unroll
  for (int r = 0; r < 4; ++r) {
    const int m = quad * 4 + r;
    slab[m * 34 + row]             = acc00[r];
    slab[m * 34 + 16 + row]        = acc01[r];
    slab[(m + 16) * 34 + row]      = acc10[r];
    slab[(m + 16) * 34 + 16 + row] = acc11[r];
  }
  __syncthreads();
#pragma unroll
  for (int i = 0; i < 4; ++i) {
    const int o = i * 256 + threadIdx.x;   // 1024 outputs per block
    const int m = o >> 5, n = o & 31;
    const int a = m * 34 + n;
    float v = red[a] + red[1088 + a] + red[2 * 1088 + a] + red[3 * 1088 + a];
    unsafeAtomicAdd(&out[(size_t)m * N_DIM + n0 + n], v);
  }
}

extern "C" void kernel_launch(void* const* d_in, const int* in_sizes, int n_in,
                              void* d_out, int out_size, void* d_ws, size_t ws_size,
                              hipStream_t stream) {
  const float* inp    = (const float*)d_in[0];
  const int4*  qw4    = (const int4*)d_in[1];
  const float* scales = (const float*)d_in[2];
  const float* amaxp  = (const float*)d_in[3];
  const float* bias   = (const float*)d_in[4];
  float* out = (float*)d_out;

  init_out_kernel<<<M_DIM * N_DIM / 4 / 256, 256, 0, stream>>>(
      (floatx4*)out, (const floatx4*)bias);

  const bool f16a = ws_size >= (size_t)M_DIM * K_DIM * sizeof(_Float16);
  if (f16a) {
    convertA_kernel<<<M_DIM * K_DIM / 4 / 256, 256, 0, stream>>>(
        (const floatx4*)inp, (half4_t*)d_ws);
    fp4_linear_kernel<true><<<MAIN_BLOCKS, 256, 0, stream>>>(
        d_ws, qw4, scales, amaxp, out);
  } else {
    fp4_linear_kernel<false><<<MAIN_BLOCKS, 256, 0, stream>>>(
        inp, qw4, scales, amaxp, out);
  }
}

// Round 3
// 236.313 us; speedup vs baseline: 1.1096x; 1.0016x over previous
//
#include <hip/hip_runtime.h>
#include <hip/hip_bf16.h>

// Problem dims (fixed by reference setup_inputs)
#define M_DIM 32
#define K_DIM 8192
#define N_DIM 8192
#define KS 32                         // K-split slices
#define KCH (K_DIM / KS)              // 256 k per slice
#define ITERS (KCH / 32)              // 8 MFMA k-steps per wave
#define NGPB 4                        // n-groups (32 cols) per block = 128 n
#define MAIN_BLOCKS ((N_DIM / 32 / NGPB) * KS)  // 64 * 32 = 2048

#define A_STRIDE (KCH + 8)            // 264 f16: 16B-aligned rows, 2-way banks (free)
#define S_STRIDE (KCH / 16 + 1)       // 17 f32: conflict-free scale reads

typedef _Float16 half8   __attribute__((ext_vector_type(8)));
typedef _Float16 half2_t __attribute__((ext_vector_type(2)));
typedef float    floatx4 __attribute__((ext_vector_type(4)));

#if defined(__has_builtin)
#if __has_builtin(__builtin_amdgcn_cvt_scalef32_pk_f16_fp4)
#define HAVE_CVT_FP4 1
#endif
#endif

#ifndef HAVE_CVT_FP4
// Manual E2M1 decode fallback: mag code m -> f16 bits t<<9,
// t = min(28m, m+28) = [0,28,30,31,32,33,34,35]; sign bit3 -> bit15.
__device__ __forceinline__ uint32_t dec2(uint32_t q) {
  uint32_t c0 = q & 0xFu, c1 = (q >> 4) & 0xFu;
  uint32_t m0 = c0 & 7u, m1 = c1 & 7u;
  uint32_t t0 = min(28u * m0, m0 + 28u);
  uint32_t t1 = min(28u * m1, m1 + 28u);
  return (t0 << 9) | ((c0 & 8u) << 12)
       | (t1 << 25) | ((c1 & 8u) << 28);
}
#endif

// 4 dwords (1 payload byte each = 2 fp4) -> 8 f16 * scale.
__device__ __forceinline__ half8 decode8(int4 q, float scale) {
  union { uint32_t u[4]; half2_t h2[4]; half8 h; } w;
#ifdef HAVE_CVT_FP4
  w.h2[0] = __builtin_amdgcn_cvt_scalef32_pk_f16_fp4((unsigned)q.x, 1.0f, 0);
  w.h2[1] = __builtin_amdgcn_cvt_scalef32_pk_f16_fp4((unsigned)q.y, 1.0f, 0);
  w.h2[2] = __builtin_amdgcn_cvt_scalef32_pk_f16_fp4((unsigned)q.z, 1.0f, 0);
  w.h2[3] = __builtin_amdgcn_cvt_scalef32_pk_f16_fp4((unsigned)q.w, 1.0f, 0);
#else
  w.u[0] = dec2((uint32_t)q.x);
  w.u[1] = dec2((uint32_t)q.y);
  w.u[2] = dec2((uint32_t)q.z);
  w.u[3] = dec2((uint32_t)q.w);
#endif
  _Float16 s = (_Float16)scale;
  half8 sv = {s, s, s, s, s, s, s, s};
  return w.h * sv;
}

// out[m][n] = bias[n], vectorized float4.
__global__ void init_out_kernel(floatx4* __restrict__ out4,
                                const floatx4* __restrict__ bias4) {
  int idx = blockIdx.x * blockDim.x + threadIdx.x;
  out4[idx] = bias4[idx & (N_DIM / 4 - 1)];
}

__global__ __launch_bounds__(256, 6) void fp4_linear_kernel(
    const float* __restrict__ inp,     // [32, 8192] f32
    const int4*  __restrict__ qw4,     // [8192][1024] int4 view of [N, K/2] i32
    const float* __restrict__ scales,  // [8192, 512] f32
    const float* __restrict__ amaxp,   // [1]
    float* __restrict__ out)           // [32, 8192] f32, pre-filled with bias
{
  __shared__ _Float16 As[M_DIM * A_STRIDE];        // 16896 B
  __shared__ float    Ss[NGPB * 32 * S_STRIDE];    // 8704 B

  const int t    = threadIdx.x;
  const int lane = t & 63;
  const int w    = t >> 6;                  // wave id: n-group within block
  const int ks   = blockIdx.x & (KS - 1);   // k-slice
  const int gb   = blockIdx.x >> 5;         // n-block [0, 64)
  const int n0   = gb * (NGPB * 32);        // block n base (128 cols)
  const int kb   = ks * KCH;                // slice k base

  const float amax = amaxp[0];

  // ---- Stage A slice (f32 -> f16), coalesced: 32 rows x 256 k. ----
  {
    const float* src = inp + kb;
    for (int p = 0; p < 4; ++p) {
      const int idx = p * 256 + t;          // [0, 1024): (m, half8-chunk)
      const int m = idx >> 5, c = idx & 31;
      const floatx4* g =
          reinterpret_cast<const floatx4*>(src + (size_t)m * K_DIM + c * 8);
      floatx4 f0 = g[0], f1 = g[1];
      half8 h;
      h[0] = (_Float16)f0[0]; h[1] = (_Float16)f0[1];
      h[2] = (_Float16)f0[2]; h[3] = (_Float16)f0[3];
      h[4] = (_Float16)f1[0]; h[5] = (_Float16)f1[1];
      h[6] = (_Float16)f1[2]; h[7] = (_Float16)f1[3];
      *reinterpret_cast<half8*>(&As[m * A_STRIDE + c * 8]) = h;
    }
  }
  // ---- Stage scales * amax, coalesced: 128 rows x 16 k-blocks. ----
  {
    const int r = t >> 1, part = t & 1;
    const float* g = scales + (size_t)(n0 + r) * (K_DIM / 16)
                   + ks * (KCH / 16) + part * 8;
    floatx4 f0 = ((const floatx4*)g)[0];
    floatx4 f1 = ((const floatx4*)g)[1];
    float* d = &Ss[r * S_STRIDE + part * 8];
    d[0] = f0[0] * amax; d[1] = f0[1] * amax;
    d[2] = f0[2] * amax; d[3] = f0[3] * amax;
    d[4] = f1[0] * amax; d[5] = f1[1] * amax;
    d[6] = f1[2] * amax; d[7] = f1[3] * amax;
  }
  __syncthreads();

  const int row  = lane & 15;   // n-within-tile (B) / m-within-tile (A)
  const int quad = lane >> 4;   // which 8 k's of the 32-k MFMA step
  const int nloc = w * 32;      // wave's local n base within block

  const int nA = n0 + nloc + row;
  const int nB = nA + 16;
  const int4* qrowA = qw4 + (size_t)nA * (K_DIM / 8);
  const int4* qrowB = qw4 + (size_t)nB * (K_DIM / 8);
  const _Float16* arow0 = &As[row * A_STRIDE];
  const _Float16* arow1 = &As[(row + 16) * A_STRIDE];
  const float* sAp = &Ss[(nloc + row) * S_STRIDE];
  const float* sBp = &Ss[(nloc + 16 + row) * S_STRIDE];

  floatx4 acc00 = {0.f, 0.f, 0.f, 0.f};
  floatx4 acc01 = {0.f, 0.f, 0.f, 0.f};
  floatx4 acc10 = {0.f, 0.f, 0.f, 0.f};
  floatx4 acc11 = {0.f, 0.f, 0.f, 0.f};

  // qweight is now the ONLY per-iter global stream (pure L1-miss traffic).
  int kq = kb + quad * 8;
  int4 qA = qrowA[kq >> 3];
  int4 qB = qrowB[kq >> 3];

#pragma unroll
  for (int it = 0; it < ITERS; ++it) {
    const int nidx = min((kq + 32) >> 3, K_DIM / 8 - 1);  // clamp: tail peel
    int4 qA_n = qrowA[nidx];
    int4 qB_n = qrowB[nidx];

    const int klo = it * 32 + quad * 8;
    half8 a0 = *reinterpret_cast<const half8*>(arow0 + klo);
    half8 a1 = *reinterpret_cast<const half8*>(arow1 + klo);
    const int kbl = klo >> 4;
    half8 bA = decode8(qA, sAp[kbl]);
    half8 bB = decode8(qB, sBp[kbl]);

    acc00 = __builtin_amdgcn_mfma_f32_16x16x32_f16(a0, bA, acc00, 0, 0, 0);
    acc01 = __builtin_amdgcn_mfma_f32_16x16x32_f16(a0, bB, acc01, 0, 0, 0);
    acc10 = __builtin_amdgcn_mfma_f32_16x16x32_f16(a1, bA, acc10, 0, 0, 0);
    acc11 = __builtin_amdgcn_mfma_f32_16x16x32_f16(a1, bB, acc11, 0, 0, 0);

    qA = qA_n; qB = qB_n;
    kq += 32;
  }

  // ---- Epilogue: D layout col = lane&15 (n), row = quad*4 + reg (m). ----
#pragma unroll
  for (int r = 0; r < 4; ++r) {
    const int m = quad * 4 + r;
    float* o0 = out + (size_t)m * N_DIM + n0 + nloc;
    float* o1 = out + (size_t)(m + 16) * N_DIM + n0 + nloc;
    unsafeAtomicAdd(o0 + row,      acc00[r]);
    unsafeAtomicAdd(o0 + 16 + row, acc01[r]);
    unsafeAtomicAdd(o1 + row,      acc10[r]);
    unsafeAtomicAdd(o1 + 16 + row, acc11[r]);
  }
}

extern "C" void kernel_launch(void* const* d_in, const int* in_sizes, int n_in,
                              void* d_out, int out_size, void* d_ws, size_t ws_size,
                              hipStream_t stream) {
  const float* inp    = (const float*)d_in[0];
  const int4*  qw4    = (const int4*)d_in[1];
  const float* scales = (const float*)d_in[2];
  const float* amaxp  = (const float*)d_in[3];
  const float* bias   = (const float*)d_in[4];
  float* out = (float*)d_out;

  init_out_kernel<<<M_DIM * N_DIM / 4 / 256, 256, 0, stream>>>(
      (floatx4*)out, (const floatx4*)bias);
  fp4_linear_kernel<<<MAIN_BLOCKS, 256, 0, stream>>>(
      inp, qw4, scales, amaxp, out);
}